// Round 4
// baseline (139.021 us; speedup 1.0000x reference)
//
#include <hip/hip_runtime.h>

// TSClusteringLayer: q[n,k] = studentT(sum_f sqrt(sum_t (x[n,t,f]-c[k,t,f])^2)), row-normalized.
// x: (2048,128,32) f32, clusters: (32,128,32) f32, out: (2048,32) f32.
//
// v4: SOFTWARE-PIPELINED register prefetch (the fix for the measured
//     load->waitcnt->compute serialization of v1..v3: ~840 stall cyc/iter).
//   Grid 256 blocks x 512 threads (8 waves). Block covers NB=8 n.
//   Wave w: nh=w&1 -> n-half (4 rows), tq=w>>1 -> t-quarter (32 iters).
//   Lane: f_grp=lane&7 (f0=4*f_grp), k_grp=(lane>>3)&7 (k0=4*k_grp).
//   Thread tile 4n x 4k x 4f; 4-stage load pipeline (loads issued 3 compute
//   phases ahead). __launch_bounds__(512,2) -> 256 VGPR budget (~210 used).
//   Cross-wave combine over tq: 2-round LDS tree (stride-65, conflict-free).
//   clusters pre-transposed to c2[t][k][f] (coalesced 1KB c-loads).

#define T_DIM 128
#define F_DIM 32
#define K_DIM 32
#define TF (T_DIM * F_DIM)
#define KF (K_DIM * F_DIM)
#define NB 8
#define SLOT_STRIDE 65

// c2[t*1024 + k*32 + f] = c[k*4096 + t*32 + f]
__global__ __launch_bounds__(256) void transpose_c_kernel(
    const float* __restrict__ c, float* __restrict__ c2)
{
    const int idx = blockIdx.x * 256 + threadIdx.x;   // 131072 total
    const int t  = idx >> 10;
    const int kf = idx & 1023;
    const int k  = kf >> 5;
    const int f  = kf & 31;
    c2[idx] = c[k * TF + t * F_DIM + f];
}

#define LOAD(s, tt) { \
    _Pragma("unroll") \
    for (int a_ = 0; a_ < 4; ++a_) \
        xv[s][a_] = *reinterpret_cast<const float4*>(xp + (size_t)a_ * TF + (tt) * F_DIM); \
    _Pragma("unroll") \
    for (int b_ = 0; b_ < 4; ++b_) \
        cv[s][b_] = *reinterpret_cast<const float4*>(cp + (size_t)(tt) * KF + b_ * F_DIM); }

#define COMP(s) { \
    _Pragma("unroll") \
    for (int a_ = 0; a_ < 4; ++a_) { \
        const float* xs_ = reinterpret_cast<const float*>(&xv[s][a_]); \
        _Pragma("unroll") \
        for (int b_ = 0; b_ < 4; ++b_) { \
            const float* cs_ = reinterpret_cast<const float*>(&cv[s][b_]); \
            _Pragma("unroll") \
            for (int j_ = 0; j_ < 4; ++j_) { \
                const float d_ = xs_[j_] - cs_[j_]; \
                acc[a_][b_][j_] += d_ * d_; } } } }

__global__ __launch_bounds__(512, 2) void tscluster_kernel(
    const float* __restrict__ x,
    const float* __restrict__ c2,
    float* __restrict__ out)
{
    __shared__ float lds[4 * 64 * SLOT_STRIDE]; // 66560 B

    const int tid   = threadIdx.x;
    const int lane  = tid & 63;
    const int w     = tid >> 6;
    const int nh    = w & 1;        // n-half within block
    const int tq    = w >> 1;       // t-quarter (32 iters each)
    const int f_grp = lane & 7;
    const int k_grp = (lane >> 3) & 7;
    const int f0 = f_grp << 2;
    const int k0 = k_grp << 2;
    const int n_base = blockIdx.x * NB + nh * 4;

    const float* xp = x  + (size_t)n_base * TF + (size_t)(tq * 32) * F_DIM + f0;
    const float* cp = c2 + (size_t)(tq * 32) * KF + k0 * F_DIM + f0;

    float acc[4][4][4];
    #pragma unroll
    for (int a = 0; a < 4; ++a)
        #pragma unroll
        for (int b = 0; b < 4; ++b)
            #pragma unroll
            for (int j = 0; j < 4; ++j)
                acc[a][b][j] = 0.0f;

    float4 xv[4][4], cv[4][4];   // 4 pipeline stages x (4 x-loads + 4 c-loads)

    LOAD(0, 0)
    LOAD(1, 1)
    LOAD(2, 2)

    #pragma unroll 1
    for (int t4 = 0; t4 < 7; ++t4) {
        const int tb = t4 * 4;
        LOAD(3, tb + 3)  COMP(0)
        LOAD(0, tb + 4)  COMP(1)
        LOAD(1, tb + 5)  COMP(2)
        LOAD(2, tb + 6)  COMP(3)
    }
    // tail: stages hold iters 28(s0), 29(s1), 30(s2); load 31 into s3
    LOAD(3, 31)
    COMP(0) COMP(1) COMP(2) COMP(3)

    // ---- combine partial accs across t-quarters (same nh) via LDS tree ----
    float* accf = &acc[0][0][0];

    // round A: tq=2,3 (w>=4) -> slots 0..3; tq=0,1 (w<4) add (w+4 has same nh)
    if (w >= 4) {
        float* dst = lds + ((size_t)(w - 4) * 64 + lane) * SLOT_STRIDE;
        #pragma unroll
        for (int i = 0; i < 64; ++i) dst[i] = accf[i];
    }
    __syncthreads();
    if (w < 4) {
        const float* src = lds + ((size_t)w * 64 + lane) * SLOT_STRIDE;
        #pragma unroll
        for (int i = 0; i < 64; ++i) accf[i] += src[i];
    }
    __syncthreads();
    // round B: tq=1 (w=2,3) -> slots 0..1; w=0,1 add (w+2 has same nh)
    if (w >= 2 && w < 4) {
        float* dst = lds + ((size_t)(w - 2) * 64 + lane) * SLOT_STRIDE;
        #pragma unroll
        for (int i = 0; i < 64; ++i) dst[i] = accf[i];
    }
    __syncthreads();

    if (w < 2) {
        const float* src = lds + ((size_t)w * 64 + lane) * SLOT_STRIDE;
        #pragma unroll
        for (int i = 0; i < 64; ++i) accf[i] += src[i];

        // n rows for this wave: n_base .. n_base+3 (nh == w)
        float dist[4][4];
        #pragma unroll
        for (int a = 0; a < 4; ++a)
            #pragma unroll
            for (int b = 0; b < 4; ++b)
                dist[a][b] = sqrtf(acc[a][b][0]) + sqrtf(acc[a][b][1]) +
                             sqrtf(acc[a][b][2]) + sqrtf(acc[a][b][3]);

        #pragma unroll
        for (int off = 1; off < 8; off <<= 1)
            #pragma unroll
            for (int a = 0; a < 4; ++a)
                #pragma unroll
                for (int b = 0; b < 4; ++b)
                    dist[a][b] += __shfl_xor(dist[a][b], off, 64);

        float qun[4][4], qs[4];
        #pragma unroll
        for (int a = 0; a < 4; ++a) {
            qs[a] = 0.0f;
            #pragma unroll
            for (int b = 0; b < 4; ++b) {
                qun[a][b] = 1.0f / (1.0f + dist[a][b] * dist[a][b]);
                qs[a] += qun[a][b];
            }
        }

        #pragma unroll
        for (int off = 8; off < 64; off <<= 1)
            #pragma unroll
            for (int a = 0; a < 4; ++a)
                qs[a] += __shfl_xor(qs[a], off, 64);

        if (f_grp == 0) {
            #pragma unroll
            for (int a = 0; a < 4; ++a) {
                float4 qv;
                qv.x = qun[a][0] / qs[a];
                qv.y = qun[a][1] / qs[a];
                qv.z = qun[a][2] / qs[a];
                qv.w = qun[a][3] / qs[a];
                *reinterpret_cast<float4*>(out + (size_t)(n_base + a) * K_DIM + k0) = qv;
            }
        }
    }
}

extern "C" void kernel_launch(void* const* d_in, const int* in_sizes, int n_in,
                              void* d_out, int out_size, void* d_ws, size_t ws_size,
                              hipStream_t stream) {
    const float* x = (const float*)d_in[0];
    const float* c = (const float*)d_in[1];
    float* out = (float*)d_out;
    float* c2  = (float*)d_ws;   // 512 KB

    transpose_c_kernel<<<dim3(131072 / 256), dim3(256), 0, stream>>>(c, c2);
    tscluster_kernel<<<dim3(2048 / NB), dim3(512), 0, stream>>>(x, c2, out);
}

// Round 5
// 104.045 us; speedup vs baseline: 1.3362x; 1.3362x over previous
//
#include <hip/hip_runtime.h>

// TSClusteringLayer: q[n,k] = studentT(sum_f sqrt(sum_t (x[n,t,f]-c[k,t,f])^2)), row-normalized.
// x: (2048,128,32) f32, clusters: (32,128,32) f32, out: (2048,32) f32.
//
// v5: v4's software pipeline with a CORRECT register budget.
//   Post-mortem findings: launch_bounds 2nd arg is waves/SIMD ->
//     v2/v3 ran with a 64-VGPR cap (accs in AGPRs, shuffle overhead),
//     v4 ran with a 128-VGPR cap (210 needed -> scratch spill, WRITE_SIZE 66MB).
//   Block 256 thr (4 waves), NB=4 n, wave w = t-quarter (32 t).
//   Lane: f_grp=lane&7 (f0=4*f_grp), k_grp=(lane>>3)&7 (k0=4*k_grp).
//   Thread tile 4n x 4k x 4f (64 accs) + 2-stage register pipeline (64 regs),
//   static stage indices (manual 2x unroll). __launch_bounds__(256,3) -> 170 cap.
//   Cross-wave combine over t-quarters: 2-round LDS tree (stride-65, conflict-free).
//   clusters pre-transposed to c2[t][k][f] (coalesced c-loads).

#define T_DIM 128
#define F_DIM 32
#define K_DIM 32
#define TF (T_DIM * F_DIM)
#define KF (K_DIM * F_DIM)
#define NB 4
#define SLOT_STRIDE 65

// c2[t*1024 + k*32 + f] = c[k*4096 + t*32 + f]
__global__ __launch_bounds__(256) void transpose_c_kernel(
    const float* __restrict__ c, float* __restrict__ c2)
{
    const int idx = blockIdx.x * 256 + threadIdx.x;   // 131072 total
    const int t  = idx >> 10;
    const int kf = idx & 1023;
    const int k  = kf >> 5;
    const int f  = kf & 31;
    c2[idx] = c[k * TF + t * F_DIM + f];
}

#define LOAD(s, tt) { \
    _Pragma("unroll") \
    for (int a_ = 0; a_ < 4; ++a_) \
        xv[s][a_] = *reinterpret_cast<const float4*>(xp + (size_t)a_ * TF + (tt) * F_DIM); \
    _Pragma("unroll") \
    for (int b_ = 0; b_ < 4; ++b_) \
        cv[s][b_] = *reinterpret_cast<const float4*>(cp + (size_t)(tt) * KF + b_ * F_DIM); }

#define COMP(s) { \
    _Pragma("unroll") \
    for (int a_ = 0; a_ < 4; ++a_) { \
        const float* xs_ = reinterpret_cast<const float*>(&xv[s][a_]); \
        _Pragma("unroll") \
        for (int b_ = 0; b_ < 4; ++b_) { \
            const float* cs_ = reinterpret_cast<const float*>(&cv[s][b_]); \
            _Pragma("unroll") \
            for (int j_ = 0; j_ < 4; ++j_) { \
                const float d_ = xs_[j_] - cs_[j_]; \
                acc[a_][b_][j_] += d_ * d_; } } } }

__global__ __launch_bounds__(256, 3) void tscluster_kernel(
    const float* __restrict__ x,
    const float* __restrict__ c2,
    float* __restrict__ out)
{
    __shared__ float lds[2 * 64 * SLOT_STRIDE]; // 33280 B

    const int tid   = threadIdx.x;
    const int lane  = tid & 63;
    const int w     = tid >> 6;        // t-quarter 0..3
    const int f_grp = lane & 7;
    const int k_grp = (lane >> 3) & 7;
    const int f0 = f_grp << 2;
    const int k0 = k_grp << 2;
    const int n0 = blockIdx.x * NB;
    const int tbase = w * 32;

    const float* xp = x  + (size_t)n0 * TF + (size_t)tbase * F_DIM + f0;
    const float* cp = c2 + (size_t)tbase * KF + k0 * F_DIM + f0;

    float acc[4][4][4];
    #pragma unroll
    for (int a = 0; a < 4; ++a)
        #pragma unroll
        for (int b = 0; b < 4; ++b)
            #pragma unroll
            for (int j = 0; j < 4; ++j)
                acc[a][b][j] = 0.0f;

    float4 xv[2][4], cv[2][4];   // 2 pipeline stages

    LOAD(0, 0)
    #pragma unroll 1
    for (int tp = 0; tp < 15; ++tp) {
        LOAD(1, 2 * tp + 1)  COMP(0)
        LOAD(0, 2 * tp + 2)  COMP(1)
    }
    LOAD(1, 31)
    COMP(0)
    COMP(1)

    // ---- combine partial accs across the 4 t-quarter waves (LDS tree) ----
    float* accf = &acc[0][0][0];

    if (w >= 2) {
        float* dst = lds + ((size_t)(w - 2) * 64 + lane) * SLOT_STRIDE;
        #pragma unroll
        for (int i = 0; i < 64; ++i) dst[i] = accf[i];
    }
    __syncthreads();
    if (w < 2) {
        const float* src = lds + ((size_t)w * 64 + lane) * SLOT_STRIDE;
        #pragma unroll
        for (int i = 0; i < 64; ++i) accf[i] += src[i];
    }
    __syncthreads();
    if (w == 1) {
        float* dst = lds + ((size_t)lane) * SLOT_STRIDE;
        #pragma unroll
        for (int i = 0; i < 64; ++i) dst[i] = accf[i];
    }
    __syncthreads();

    if (w == 0) {
        const float* src = lds + ((size_t)lane) * SLOT_STRIDE;
        #pragma unroll
        for (int i = 0; i < 64; ++i) accf[i] += src[i];

        float dist[4][4];
        #pragma unroll
        for (int a = 0; a < 4; ++a)
            #pragma unroll
            for (int b = 0; b < 4; ++b)
                dist[a][b] = sqrtf(acc[a][b][0]) + sqrtf(acc[a][b][1]) +
                             sqrtf(acc[a][b][2]) + sqrtf(acc[a][b][3]);

        #pragma unroll
        for (int off = 1; off < 8; off <<= 1)
            #pragma unroll
            for (int a = 0; a < 4; ++a)
                #pragma unroll
                for (int b = 0; b < 4; ++b)
                    dist[a][b] += __shfl_xor(dist[a][b], off, 64);

        float qun[4][4], qs[4];
        #pragma unroll
        for (int a = 0; a < 4; ++a) {
            qs[a] = 0.0f;
            #pragma unroll
            for (int b = 0; b < 4; ++b) {
                qun[a][b] = 1.0f / (1.0f + dist[a][b] * dist[a][b]);
                qs[a] += qun[a][b];
            }
        }

        #pragma unroll
        for (int off = 8; off < 64; off <<= 1)
            #pragma unroll
            for (int a = 0; a < 4; ++a)
                qs[a] += __shfl_xor(qs[a], off, 64);

        if (f_grp == 0) {
            #pragma unroll
            for (int a = 0; a < 4; ++a) {
                float4 qv;
                qv.x = qun[a][0] / qs[a];
                qv.y = qun[a][1] / qs[a];
                qv.z = qun[a][2] / qs[a];
                qv.w = qun[a][3] / qs[a];
                *reinterpret_cast<float4*>(out + (size_t)(n0 + a) * K_DIM + k0) = qv;
            }
        }
    }
}

extern "C" void kernel_launch(void* const* d_in, const int* in_sizes, int n_in,
                              void* d_out, int out_size, void* d_ws, size_t ws_size,
                              hipStream_t stream) {
    const float* x = (const float*)d_in[0];
    const float* c = (const float*)d_in[1];
    float* out = (float*)d_out;
    float* c2  = (float*)d_ws;   // 512 KB

    transpose_c_kernel<<<dim3(131072 / 256), dim3(256), 0, stream>>>(c, c2);
    tscluster_kernel<<<dim3(2048 / NB), dim3(256), 0, stream>>>(x, c2, out);
}

// Round 6
// 103.969 us; speedup vs baseline: 1.3371x; 1.0007x over previous
//
#include <hip/hip_runtime.h>
#include <hip/hip_bf16.h>

// TSClusteringLayer via quadratic form + MFMA (bf16).
//   q[n,k] = norm_k( 1/(1+dist^2) ),  dist[n,k] = sum_f sqrt(max(x2[n,f]+c2[k,f]-2*xc[n,k,f],0))
//   xc[n,k,f] = sum_t x[n,t,f]*c[k,t,f]  -> 32 GEMMs (2048x128)*(128x32), one per f.
// v6 rationale: v1-v5 (direct VALU) all stuck at 52-63us, latency-bound per t-iter.
//   This restructures to ONE latency exposure per wave + MFMA for the contraction.
// Pass 1: transpose+pack  x[2048][128][32]f32 -> xT[32][2048][128]bf16 + x2[32][2048]f32
// Pass 2: same for clusters (4 blocks).
// Pass 3: per (n-tile 32, f-group 8): 8 waves x 1 f: 8x mfma_f32_32x32x16_bf16
//         (K=t), epilogue sqrt, LDS-atomic sum over 8 f -> partial[4][2048][32].
// Pass 4: sum 4 partials, Student-t (alpha=1 -> exponent 1), normalize over k.
// bf16 error budget: dist err ~0.02 -> q err ~2e-6 << 6.8e-4 threshold.

typedef __attribute__((ext_vector_type(8)))  short  short8;   // 8 bf16 = 4 VGPR
typedef __attribute__((ext_vector_type(16))) float  float16;  // MFMA acc

#define NTOT 2048
#define TDIM 128
#define FDIM 32
#define KDIM 32

// ---- ws carving (bytes) ----
#define OFF_XT   0                        // 32*2048*128*2 = 16777216
#define OFF_CT   16777216                 // 32*32*128*2   = 262144
#define OFF_X2   17039360                 // 32*2048*4     = 262144
#define OFF_C2   17301504                 // 32*32*4       = 4096
#define OFF_PART 17305600                 // 4*2048*32*4   = 1048576
// total 18354176 B

// src[R][128][32] f32 -> dstT[32][Rtot][128] bf16-bits, dst2[32][Rtot] = sum_t x_bf16^2
__global__ __launch_bounds__(256) void transpose_pack_kernel(
    const float* __restrict__ src,
    unsigned short* __restrict__ dstT,
    float* __restrict__ dst2,
    int Rtot)
{
    __shared__ unsigned short lds[8 * 128 * 32]; // 64 KB, bf16, natural [n][t][f]
    const int tid = threadIdx.x;
    const int r0 = blockIdx.x * 8;

    // phase 1: coalesced float4 load + bf16 convert + linear ds_write
    const float* sp = src + (size_t)r0 * (TDIM * FDIM);
    #pragma unroll
    for (int i = 0; i < 32; ++i) {
        const float4 v = *reinterpret_cast<const float4*>(sp + ((size_t)i * 256 + tid) * 4);
        union { __hip_bfloat16 h; unsigned short u; } c0, c1, c2, c3;
        c0.h = __float2bfloat16(v.x); c1.h = __float2bfloat16(v.y);
        c2.h = __float2bfloat16(v.z); c3.h = __float2bfloat16(v.w);
        uint2 pk;
        pk.x = (unsigned)c0.u | ((unsigned)c1.u << 16);
        pk.y = (unsigned)c2.u | ((unsigned)c3.u << 16);
        *reinterpret_cast<uint2*>(&lds[((size_t)i * 256 + tid) * 4]) = pk;
    }
    __syncthreads();

    // phase 2: thread (f = tid&31, nl = tid>>5) emits one 128-t bf16 row + x2
    const int f = tid & 31, nl = tid >> 5;
    const int rg = r0 + nl;
    float x2 = 0.f;
    unsigned short* op = dstT + ((size_t)f * Rtot + rg) * TDIM;
    #pragma unroll 4
    for (int t8 = 0; t8 < 16; ++t8) {
        uint4 ow;
        unsigned* owp = reinterpret_cast<unsigned*>(&ow);
        #pragma unroll
        for (int p = 0; p < 4; ++p) {
            const unsigned short ua = lds[(nl * 128 + t8 * 8 + p * 2    ) * 32 + f];
            const unsigned short ub = lds[(nl * 128 + t8 * 8 + p * 2 + 1) * 32 + f];
            const float fa = __uint_as_float((unsigned)ua << 16);
            const float fb = __uint_as_float((unsigned)ub << 16);
            x2 = fmaf(fa, fa, x2);
            x2 = fmaf(fb, fb, x2);
            owp[p] = (unsigned)ua | ((unsigned)ub << 16);
        }
        *reinterpret_cast<uint4*>(op + t8 * 8) = ow;
    }
    dst2[(size_t)f * Rtot + rg] = x2;
}

// 256 blocks x 512 thr: block = (n-tile of 32) x (f-group of 8); wave = 1 f.
__global__ __launch_bounds__(512, 2) void xc_mfma_kernel(
    const unsigned short* __restrict__ xT,   // [32][2048][128]
    const unsigned short* __restrict__ cT,   // [32][32][128]
    const float* __restrict__ x2T,           // [32][2048]
    const float* __restrict__ c2T,           // [32][32]
    float* __restrict__ part)                // [4][2048][32]
{
    __shared__ float dist[1024]; // [32 n][32 k]
    const int tid = threadIdx.x;
    const int l = tid & 63, w = tid >> 6;
    const int nt = blockIdx.x & 63, fg = blockIdx.x >> 6;
    const int n0 = nt * 32;
    const int f  = fg * 8 + w;

    if (tid < 256) reinterpret_cast<float4*>(dist)[tid] = make_float4(0.f, 0.f, 0.f, 0.f);
    __syncthreads();

    const int m = l & 31, g = l >> 5;   // m: A-row (n) AND B-col (k); g: k-half
    const unsigned short* ap = xT + ((size_t)f * NTOT + (n0 + m)) * TDIM + g * 8;
    const unsigned short* bp = cT + ((size_t)f * KDIM + m) * TDIM + g * 8;

    short8 av[8], bv[8];
    #pragma unroll
    for (int c = 0; c < 8; ++c) {
        av[c] = *reinterpret_cast<const short8*>(ap + c * 16);
        bv[c] = *reinterpret_cast<const short8*>(bp + c * 16);
    }

    float16 acc;
    #pragma unroll
    for (int r = 0; r < 16; ++r) acc[r] = 0.f;
    #pragma unroll
    for (int c = 0; c < 8; ++c)
        acc = __builtin_amdgcn_mfma_f32_32x32x16_bf16(av[c], bv[c], acc, 0, 0, 0);

    // epilogue: ed = sqrt(max(x2 + c2 - 2*xc, 0)); sum over this block's 8 f via LDS atomics
    const float c2v = c2T[f * KDIM + m];
    #pragma unroll
    for (int r = 0; r < 16; ++r) {
        const int rm = (r & 3) + 8 * (r >> 2) + 4 * g;   // m101-verified C/D row map
        const float x2v = x2T[(size_t)f * NTOT + n0 + rm];
        const float sq = x2v + c2v - 2.0f * acc[r];
        const float ed = sqrtf(fmaxf(sq, 0.0f));
        atomicAdd(&dist[rm * 32 + m], ed);
    }
    __syncthreads();

    float* pb = part + (size_t)fg * (NTOT * KDIM) + (size_t)n0 * KDIM;
    pb[tid]       = dist[tid];
    pb[tid + 512] = dist[tid + 512];
}

// sum 4 f-group partials, Student-t, normalize over k. 256 blocks x 256 thr.
__global__ __launch_bounds__(256) void qnorm_kernel(
    const float* __restrict__ part, float* __restrict__ out)
{
    const int tid = threadIdx.x;
    const int l = tid & 63, wv = tid >> 6;
    const int n = blockIdx.x * 8 + wv * 2 + (l >> 5);
    const int k = l & 31;
    const size_t idx = (size_t)n * KDIM + k;
    const float d = part[idx]
                  + part[idx + 1 * NTOT * KDIM]
                  + part[idx + 2 * NTOT * KDIM]
                  + part[idx + 3 * NTOT * KDIM];
    const float qun = 1.0f / (1.0f + d * d);   // alpha=1 -> exponent (a+1)/2 = 1
    float s = qun;
    #pragma unroll
    for (int off = 1; off < 32; off <<= 1) s += __shfl_xor(s, off, 64);
    out[idx] = qun / s;
}

extern "C" void kernel_launch(void* const* d_in, const int* in_sizes, int n_in,
                              void* d_out, int out_size, void* d_ws, size_t ws_size,
                              hipStream_t stream) {
    const float* x = (const float*)d_in[0];
    const float* c = (const float*)d_in[1];
    float* out = (float*)d_out;
    char* ws = (char*)d_ws;

    unsigned short* xT  = (unsigned short*)(ws + OFF_XT);
    unsigned short* cT  = (unsigned short*)(ws + OFF_CT);
    float*          x2T = (float*)(ws + OFF_X2);
    float*          c2T = (float*)(ws + OFF_C2);
    float*          prt = (float*)(ws + OFF_PART);

    transpose_pack_kernel<<<dim3(NTOT / 8), dim3(256), 0, stream>>>(x, xT, x2T, NTOT);
    transpose_pack_kernel<<<dim3(KDIM / 8), dim3(256), 0, stream>>>(c, cT, c2T, KDIM);
    xc_mfma_kernel<<<dim3(256), dim3(512), 0, stream>>>(xT, cT, x2T, c2T, prt);
    qnorm_kernel<<<dim3(NTOT / 8), dim3(256), 0, stream>>>(prt, out);
}